// Round 1
// baseline (156.188 us; speedup 1.0000x reference)
//
#include <hip/hip_runtime.h>

#define WAYS 5
#define NSUP 25
#define NQ 30
#define HW 441
#define CH 128
#define MPAD 448
#define NWAY 2208
#define NVALID 2205
#define NCHUNKS 4
#define SUBS_PER_CHUNK 18
#define TOTSUBS 69

typedef __attribute__((ext_vector_type(8))) short bh8;
typedef __attribute__((ext_vector_type(4))) float f32x4;

__device__ __forceinline__ unsigned short f2bf(float f) {
  unsigned int u = __float_as_uint(f);
  unsigned int r = (u + 0x7fffu + ((u >> 16) & 1u)) >> 16;
  return (unsigned short)r;
}

// ---------------- kernel 0: zero the pad rows of Zq / Zs ----------------
__global__ __launch_bounds__(256) void k_pad(unsigned short* __restrict__ Zq,
                                             unsigned short* __restrict__ Zs) {
  int i = blockIdx.x * 256 + threadIdx.x;
  if (i < NQ * 7 * CH) {
    int q = i / (7 * CH); int rem = i % (7 * CH);
    Zq[((size_t)q * MPAD + HW + rem / CH) * CH + (rem % CH)] = 0;
  } else {
    int j = i - NQ * 7 * CH;
    if (j < WAYS * 3 * CH) {
      int w = j / (3 * CH); int rem = j % (3 * CH);
      Zs[((size_t)w * NWAY + NVALID + rem / CH) * CH + (rem % CH)] = 0;
    }
  }
}

// ---------------- kernel 1: transpose + L2 normalize + bf16 cast ----------------
// input x[b][c][hw]; output desc[row][c] bf16 (query -> Zq, support -> Zs grouped by way)
__global__ __launch_bounds__(256) void k_norm(const float* __restrict__ sup,
                                              const float* __restrict__ lab,
                                              const float* __restrict__ qry,
                                              unsigned short* __restrict__ Zq,
                                              unsigned short* __restrict__ Zs) {
  int img = blockIdx.x / 7;
  int chunk = blockIdx.x % 7;
  int hw0 = chunk * 64;
  int hwn = min(64, HW - hw0);
  int tid = threadIdx.x;
  __shared__ float tile[CH * 65];
  __shared__ int s_way, s_rank;

  const float* src = (img < NSUP) ? (sup + (size_t)img * CH * HW)
                                  : (qry + (size_t)(img - NSUP) * CH * HW);
  int j = tid & 63, c0 = tid >> 6;
  if (j < hwn) {
    for (int c = c0; c < CH; c += 4)
      tile[c * 65 + j] = src[(size_t)c * HW + hw0 + j];
  }
  if (tid == 0) {
    int myway = 0, myrank = 0;
    if (img < NSUP) {
      float best = lab[img * WAYS];
      for (int t = 1; t < WAYS; ++t) { float v = lab[img * WAYS + t]; if (v > best) { best = v; myway = t; } }
      for (int s = 0; s < img; ++s) {
        int w2 = 0; float b2 = lab[s * WAYS];
        for (int t = 1; t < WAYS; ++t) { float v = lab[s * WAYS + t]; if (v > b2) { b2 = v; w2 = t; } }
        if (w2 == myway) myrank++;
      }
    }
    s_way = myway; s_rank = myrank;
  }
  __syncthreads();

  int jj = tid >> 2, part = tid & 3;
  if (jj >= hwn) return;  // partner lanes (t^1,t^2) share jj, exit together
  float s = 0.f;
  int cb = part * 32;
  for (int c = cb; c < cb + 32; ++c) { float v = tile[c * 65 + jj]; s += v * v; }
  s += __shfl_xor(s, 1, 64);
  s += __shfl_xor(s, 2, 64);
  float inv = 1.0f / fmaxf(sqrtf(s), 1e-12f);

  unsigned short* dst;
  if (img < NSUP)
    dst = Zs + ((size_t)s_way * NWAY + (size_t)s_rank * HW + hw0 + jj) * CH;
  else
    dst = Zq + ((size_t)(img - NSUP) * MPAD + hw0 + jj) * CH;

  for (int c = cb; c < cb + 32; c += 4) {
    ushort4 o;
    o.x = f2bf(tile[(c + 0) * 65 + jj] * inv);
    o.y = f2bf(tile[(c + 1) * 65 + jj] * inv);
    o.z = f2bf(tile[(c + 2) * 65 + jj] * inv);
    o.w = f2bf(tile[(c + 3) * 65 + jj] * inv);
    *(ushort4*)(dst + c) = o;
  }
}

// ---------------- kernel 2: fused GEMM (mfma bf16) + per-row top-3 ----------------
// block = (q, way, n-chunk); 4 waves, each wave = 7 m-tiles (112 query rows).
// D[n][m] = support . query^T ; C layout: m = lane&15, n = (lane>>4)*4 + reg.
__global__ __launch_bounds__(256, 2) void k_sim(const unsigned short* __restrict__ Zq,
                                                const unsigned short* __restrict__ Zs,
                                                float* __restrict__ part) {
  int bid = blockIdx.x;
  int cid = bid & 3;
  int w = (bid >> 2) % WAYS;
  int q = bid / (WAYS * NCHUNKS);
  int tid = threadIdx.x;
  int wv = tid >> 6;
  int l = tid & 63;
  int lm = l & 15, lg = l >> 4;
  __shared__ __align__(16) unsigned short sbuf[2][32 * CH];  // 2 x 8KB, XOR-swizzled

  // query fragments: 7 m-tiles x 4 k-steps, held in registers
  bh8 bfrag[7][4];
  int m0 = wv * 112;
#pragma unroll
  for (int mt = 0; mt < 7; ++mt)
#pragma unroll
    for (int ks = 0; ks < 4; ++ks) {
      const unsigned short* p = Zq + ((size_t)q * MPAD + m0 + mt * 16 + lm) * CH + ks * 32 + lg * 8;
      bfrag[mt][ks] = *(const bh8*)p;
    }

  float t0[7], t1[7], t2[7];
#pragma unroll
  for (int i = 0; i < 7; ++i) { t0[i] = -1e30f; t1[i] = -1e30f; t2[i] = -1e30f; }

  int nsub0 = cid * SUBS_PER_CHUNK;
  int nsubs = min(SUBS_PER_CHUNK, TOTSUBS - nsub0);

  const int4* gsrc0 = (const int4*)(Zs + ((size_t)w * NWAY + nsub0 * 32) * CH);

  int4 stg[2];
  // prologue: stage sub-chunk 0 into buf 0 (swizzled: lds[row][c] = g[row][c ^ (row&7)])
  stg[0] = gsrc0[tid];
  stg[1] = gsrc0[tid + 256];
#pragma unroll
  for (int i = 0; i < 2; ++i) {
    int lin = tid + i * 256;
    int row = lin >> 4, gc = lin & 15;
    *(int4*)((char*)(&sbuf[0][0]) + row * 256 + ((gc ^ (row & 7)) * 16)) = stg[i];
  }
  __syncthreads();

  for (int s = 0; s < nsubs; ++s) {
    int cur = s & 1;
    bool more = (s + 1 < nsubs);
    if (more) {  // issue next sub-chunk's global loads early (latency hides under MFMA)
      const int4* gs = gsrc0 + (size_t)(s + 1) * 512;
      stg[0] = gs[tid];
      stg[1] = gs[tid + 256];
    }
#pragma unroll
    for (int tl = 0; tl < 2; ++tl) {
      int nbase = (nsub0 + s) * 32 + tl * 16;
      bh8 af[4];
#pragma unroll
      for (int ks = 0; ks < 4; ++ks) {
        int row = tl * 16 + lm;
        int chn = (ks * 4 + lg) ^ (row & 7);
        af[ks] = *(const bh8*)((const char*)(&sbuf[cur][0]) + row * 256 + chn * 16);
      }
      bool edge = (nbase + 16 > NVALID);
#pragma unroll
      for (int mt = 0; mt < 7; ++mt) {
        f32x4 acc = {0.f, 0.f, 0.f, 0.f};
#pragma unroll
        for (int ks = 0; ks < 4; ++ks)
          acc = __builtin_amdgcn_mfma_f32_16x16x32_bf16(af[ks], bfrag[mt][ks], acc, 0, 0, 0);
#pragma unroll
        for (int r = 0; r < 4; ++r) {
          float v = acc[r];
          if (edge) { if (nbase + lg * 4 + r >= NVALID) v = -1e30f; }
          float a0 = fminf(t0[mt], v); t0[mt] = fmaxf(t0[mt], v);
          float a1 = fminf(t1[mt], a0); t1[mt] = fmaxf(t1[mt], a0);
          t2[mt] = fmaxf(t2[mt], a1);
        }
      }
    }
    if (more) {  // write next buffer (other half of dbuf; prev-iter barrier made it dead)
      int nb = cur ^ 1;
#pragma unroll
      for (int i = 0; i < 2; ++i) {
        int lin = tid + i * 256;
        int row = lin >> 4, gc = lin & 15;
        *(int4*)((char*)(&sbuf[nb][0]) + row * 256 + ((gc ^ (row & 7)) * 16)) = stg[i];
      }
    }
    __syncthreads();
  }

  // merge the 4 lane-groups' partial top-3 (lanes l^16, l^32 share m = l&15)
#pragma unroll
  for (int mt = 0; mt < 7; ++mt) {
    float a0 = t0[mt], a1 = t1[mt], a2 = t2[mt];
#pragma unroll
    for (int off = 16; off <= 32; off <<= 1) {
      float b0 = __shfl_xor(a0, off, 64);
      float b1 = __shfl_xor(a1, off, 64);
      float b2 = __shfl_xor(a2, off, 64);
      float x, y;
      x = fminf(a0, b0); a0 = fmaxf(a0, b0); y = fminf(a1, x); a1 = fmaxf(a1, x); a2 = fmaxf(a2, y);
      x = fminf(a0, b1); a0 = fmaxf(a0, b1); y = fminf(a1, x); a1 = fmaxf(a1, x); a2 = fmaxf(a2, y);
      x = fminf(a0, b2); a0 = fmaxf(a0, b2); y = fminf(a1, x); a1 = fmaxf(a1, x); a2 = fmaxf(a2, y);
    }
    int m_local = m0 + mt * 16 + lm;
    if (lg == 0 && m_local < HW) {
      float* p = part + ((((size_t)q * WAYS + w) * NCHUNKS + cid) * HW + m_local) * 3;
      p[0] = a0; p[1] = a1; p[2] = a2;
    }
  }
}

// ---------------- kernel 3: merge chunk-partial top-3s, reduce to scores ----------------
__global__ __launch_bounds__(256) void k_reduce(const float* __restrict__ part,
                                                float* __restrict__ out) {
  int qw = blockIdx.x;  // q*5 + w
  int tid = threadIdx.x;
  float sum = 0.f;
  for (int m = tid; m < HW; m += 256) {
    const float* p0 = part + ((size_t)qw * NCHUNKS) * HW * 3 + (size_t)m * 3;
    float a0 = p0[0], a1 = p0[1], a2 = p0[2];
#pragma unroll
    for (int c = 1; c < NCHUNKS; ++c) {
      const float* pc = part + ((size_t)qw * NCHUNKS + c) * HW * 3 + (size_t)m * 3;
      float x, y, b;
      b = pc[0]; x = fminf(a0, b); a0 = fmaxf(a0, b); y = fminf(a1, x); a1 = fmaxf(a1, x); a2 = fmaxf(a2, y);
      b = pc[1]; x = fminf(a0, b); a0 = fmaxf(a0, b); y = fminf(a1, x); a1 = fmaxf(a1, x); a2 = fmaxf(a2, y);
      b = pc[2]; x = fminf(a0, b); a0 = fmaxf(a0, b); y = fminf(a1, x); a1 = fmaxf(a1, x); a2 = fmaxf(a2, y);
    }
    sum += a0 + a1 + a2;
  }
#pragma unroll
  for (int off = 1; off < 64; off <<= 1) sum += __shfl_xor(sum, off, 64);
  __shared__ float red[4];
  if ((tid & 63) == 0) red[tid >> 6] = sum;
  __syncthreads();
  if (tid == 0) out[qw] = (red[0] + red[1] + red[2] + red[3]) * (1.0f / 1323.0f);
}

extern "C" void kernel_launch(void* const* d_in, const int* in_sizes, int n_in,
                              void* d_out, int out_size, void* d_ws, size_t ws_size,
                              hipStream_t stream) {
  const float* sup = (const float*)d_in[0];
  const float* lab = (const float*)d_in[1];
  const float* qry = (const float*)d_in[2];
  float* out = (float*)d_out;
  char* ws = (char*)d_ws;

  unsigned short* Zq = (unsigned short*)ws;                      // 30*448*128*2  = 3,440,640 B
  unsigned short* Zs = (unsigned short*)(ws + 3440640);          // 5*2208*128*2  = 2,826,240 B
  float* part = (float*)(ws + 3440640 + 2826240);                // 30*5*4*441*3*4 = 3,175,200 B

  hipLaunchKernelGGL(k_pad, dim3(113), dim3(256), 0, stream, Zq, Zs);
  hipLaunchKernelGGL(k_norm, dim3(55 * 7), dim3(256), 0, stream, sup, lab, qry, Zq, Zs);
  hipLaunchKernelGGL(k_sim, dim3(NQ * WAYS * NCHUNKS), dim3(256), 0, stream, Zq, Zs, part);
  hipLaunchKernelGGL(k_reduce, dim3(NQ * WAYS), dim3(256), 0, stream, part, out);
}